// Round 13
// baseline (245.733 us; speedup 1.0000x reference)
//
#include <hip/hip_runtime.h>
#include <hip/hip_bf16.h>

// Problem constants
#define N_NODES 30000
#define NPAD    30080            // 235 * 128
#define N_EDGES 480000
#define N_RELS  8
#define NB_SCAN 118              // ceil(30000/256)

typedef short bf16x8 __attribute__((ext_vector_type(8)));
typedef float f32x4  __attribute__((ext_vector_type(4)));

__device__ __forceinline__ unsigned short f2bf(float f) {
    unsigned u = __float_as_uint(f);
    u += 0x7fffu + ((u >> 16) & 1u);     // round-to-nearest-even
    return (unsigned short)(u >> 16);
}
__device__ __forceinline__ float bf2f(unsigned short h) {
    return __uint_as_float(((unsigned)h) << 16);
}
__device__ __forceinline__ ushort2 pk2bf(float a, float b) {  // v_cvt_pk_bf16_f32 (RNE)
    __hip_bfloat162 t = __float22bfloat162_rn(float2{a, b});
    union { __hip_bfloat162 h; ushort2 u; } cv; cv.h = t; return cv.u;
}

__device__ __forceinline__ void load_lds16(const void* g, void* l) {
    __builtin_amdgcn_global_load_lds(
        (const __attribute__((address_space(1))) unsigned int*)g,
        (__attribute__((address_space(3))) unsigned int*)l,
        16, 0, 0);
}

// ---------------------------------------------------------------------------
// K1 (fused prep): blocks [0,3760) cast x fp32->bf16 (pad rows to NPAD);
//                  blocks [3760,5808) transpose conv_weights -> wt bf16;
//                  blocks [5808,7683) histogram of edge dst.
// ---------------------------------------------------------------------------
__global__ void prep_kernel(const float* __restrict__ x, unsigned short* __restrict__ xbf,
                            const float* __restrict__ cw, unsigned short* __restrict__ wt,
                            const int* __restrict__ edst, int* __restrict__ counts) {
    int b = blockIdx.x;
    if (b < 3760) {
        int t = b * 256 + threadIdx.x;               // 962560 threads, 8 elems each
        int base = t * 8;
        int n = base >> 8;
        unsigned short h[8];
        if (n < N_NODES) {
            float4 a = *(const float4*)(x + base);
            float4 c = *(const float4*)(x + base + 4);
            h[0]=f2bf(a.x); h[1]=f2bf(a.y); h[2]=f2bf(a.z); h[3]=f2bf(a.w);
            h[4]=f2bf(c.x); h[5]=f2bf(c.y); h[6]=f2bf(c.z); h[7]=f2bf(c.w);
        } else {
            #pragma unroll
            for (int i = 0; i < 8; ++i) h[i] = 0;
        }
        uint4 o;
        o.x = (unsigned)h[0] | ((unsigned)h[1] << 16);
        o.y = (unsigned)h[2] | ((unsigned)h[3] << 16);
        o.z = (unsigned)h[4] | ((unsigned)h[5] << 16);
        o.w = (unsigned)h[6] | ((unsigned)h[7] << 16);
        *(uint4*)(xbf + base) = o;
    } else if (b < 5808) {
        int o = (b - 3760) * 256 + threadIdx.x;      // 524288 threads
        int i = o & 255;
        int c = (o >> 8) & 255;
        int r = o >> 16;
        float v = cw[(((size_t)r * 4 + (c >> 6)) * 256 + i) * 64 + (c & 63)];
        wt[o] = f2bf(v);
    } else {
        int e = (b - 5808) * 256 + threadIdx.x;      // 480000 threads
        if (e < N_EDGES) atomicAdd(&counts[edst[e]], 1);
    }
}

// ---------------------------------------------------------------------------
// K2a: per-block exclusive scan of counts -> locexcl, block sums -> bsum
// ---------------------------------------------------------------------------
__global__ void scan1_kernel(const int* __restrict__ counts, int* __restrict__ locexcl,
                             int* __restrict__ bsum) {
    __shared__ int sm[256];
    int tid = threadIdx.x;
    int idx = blockIdx.x * 256 + tid;
    int v = (idx < N_NODES) ? counts[idx] : 0;
    sm[tid] = v;
    __syncthreads();
    for (int o = 1; o < 256; o <<= 1) {
        int t = (tid >= o) ? sm[tid - o] : 0;
        __syncthreads();
        sm[tid] += t;
        __syncthreads();
    }
    int incl = sm[tid];
    if (idx < N_NODES) locexcl[idx] = incl - v;
    if (tid == 255) bsum[blockIdx.x] = incl;
}

// ---------------------------------------------------------------------------
// K2b (merged old scan2+scan3): block b sums bsum[0..b) directly (118 values,
// trivial), adds locexcl -> offsets (+cursor copy). One fewer launch.
// ---------------------------------------------------------------------------
__global__ void scan23_kernel(const int* __restrict__ locexcl, const int* __restrict__ bsum,
                              int* __restrict__ offsets, int* __restrict__ cursor) {
    __shared__ int red[256];
    int b   = blockIdx.x;
    int tid = threadIdx.x;
    int v = (tid < b) ? bsum[tid] : 0;    // tid < b <= 117 < 128 -> in bounds
    red[tid] = v;
    __syncthreads();
    #pragma unroll
    for (int s = 128; s > 0; s >>= 1) {
        if (tid < s) red[tid] += red[tid + s];
        __syncthreads();
    }
    int bpre = red[0];                    // sum of bsum[0..b)
    int idx = b * 256 + tid;
    if (idx < N_NODES) {
        int o = bpre + locexcl[idx];
        offsets[idx] = o;
        cursor[idx]  = o;
    }
    if (idx == 0) offsets[N_NODES] = N_EDGES;
}

// ---------------------------------------------------------------------------
// K3: bf16 MFMA GEMM  feat[r][n][c] = sum_k xbf[n][k] * wt[r][c][k]
//     128x128 tile, BK=32, 4 waves, global_load_lds(16B), XOR chunk swizzle,
//     mfma(wt_frag, x_frag), XCD remap work=(bid&7)*470+(bid>>3).
//     Stage-ahead single-barrier double-buffer using ONLY __syncthreads
//     (R12-verified: gemm 58.6 us, FETCH 20.5->16.8 MB, MfmaUtil 22%).
//     Epilogue A: proj reduction (wave-private LDS bufs, in dead buf0).
//     Epilogue B: feat via SINGLE-PASS per-wave LDS bounce -> dwordx4 stores
//     (one wave instruction = 8 full 128B lines; R4: 70.3 -> 59.5 us).
// ---------------------------------------------------------------------------
__global__ __launch_bounds__(256) void gemm_kernel(
    const unsigned short* __restrict__ xbf,   // [NPAD][256]
    const unsigned short* __restrict__ wt,    // [R][256][256]
    const float* __restrict__ attn_l,         // [R][4][64]
    const float* __restrict__ attn_r,
    unsigned short* __restrict__ feat,        // [R][NPAD][256]
    float* __restrict__ projl,                // [R][NPAD][4]
    float* __restrict__ projr)
{
    __shared__ __align__(16) unsigned char smem[36864];

    const int tid  = threadIdx.x;
    const int lane = tid & 63;
    const int w    = tid >> 6;        // wave 0..3
    const int wm   = w >> 1;          // wave node-block (0/1)
    const int wn   = w & 1;           // wave col-block (0/1)
    const int quad = lane >> 4;
    const int l15  = lane & 15;

    const int bid  = blockIdx.x;               // 0..3759
    const int work = (bid & 7) * 470 + (bid >> 3);
    const int mt   = work >> 4;                // 0..234
    const int r    = (work >> 1) & 7;          // relation
    const int nt   = work & 1;                 // col tile (0/1)
    const int mbase = mt * 128;
    const int nbase = nt * 128;

    const unsigned short* Asrc = xbf + (size_t)mbase * 256;
    const unsigned short* Bsrc = wt + ((size_t)r * 256 + nbase) * 256;

    f32x4 acc[4][4] = {};   // acc[i][j]: cols i*16+quad*4+e of node j*16+l15

    const int srow = w * 16 + (lane >> 2);
    const int c0   = lane & 3;

    // stage K-tile kt into buffer b (A at +0, B at +8192; buffers 16KB apart)
    auto stage = [&](int kt, int b) {
        int k0 = kt * 32;
        unsigned char* dst = smem + b * 16384;
        #pragma unroll
        for (int n = 0; n < 2; ++n) {
            int row = n * 64 + srow;
            int c   = c0 ^ ((row >> 1) & 3);
            load_lds16(Asrc + (size_t)row * 256 + k0 + c * 8, dst + (n * 256 + w * 64) * 16);
        }
        #pragma unroll
        for (int n = 0; n < 2; ++n) {
            int row = n * 64 + srow;
            int c   = c0 ^ ((row >> 1) & 3);
            load_lds16(Bsrc + (size_t)row * 256 + k0 + c * 8, dst + 8192 + (n * 256 + w * 64) * 16);
        }
    };

    stage(0, 0);

    #pragma unroll
    for (int kt = 0; kt < 8; ++kt) {
        // __syncthreads drains this wave's outstanding global_load_lds
        // (vmcnt(0)) then barriers: buf[kt&1] is fully staged + visible.
        __syncthreads();
        // stage NEXT tile into the other buffer: that buffer's last readers
        // were in iter kt-1, and the barrier above proves all waves passed it.
        if (kt < 7) stage(kt + 1, (kt + 1) & 1);

        const unsigned char* buf = smem + (kt & 1) * 16384;

        bf16x8 xf[4], wf[4];
        #pragma unroll
        for (int j = 0; j < 4; ++j) {          // x rows (node fragments)
            int row = wm * 64 + j * 16 + l15;
            int cc  = quad ^ ((row >> 1) & 3);
            xf[j] = *(const bf16x8*)(buf + row * 64 + cc * 16);
        }
        #pragma unroll
        for (int i = 0; i < 4; ++i) {          // wt rows (col fragments)
            int row = wn * 64 + i * 16 + l15;
            int cc  = quad ^ ((row >> 1) & 3);
            wf[i] = *(const bf16x8*)(buf + 8192 + row * 64 + cc * 16);
        }

        #pragma unroll
        for (int i = 0; i < 4; ++i)
            #pragma unroll
            for (int j = 0; j < 4; ++j)
                acc[i][j] = __builtin_amdgcn_mfma_f32_16x16x32_bf16(wf[i], xf[j], acc[i][j], 0, 0, 0);
    }
    // NOTE: no barrier needed here. Epilogue A writes wave-private regions in
    // buf0 bytes [0,13312); any straggler wave is still reading buf1
    // ([16384,32768)) — disjoint. Epilogue A reads are same-wave only.

    // ---- epilogue A: fused attention projections (wave-private LDS bufs)
    const int head = nt * 2 + wn;
    float alv[4][4], arv[4][4];
    #pragma unroll
    for (int i = 0; i < 4; ++i)
        #pragma unroll
        for (int e = 0; e < 4; ++e) {
            int c = i * 16 + quad * 4 + e;
            alv[i][e] = attn_l[((size_t)r * 4 + head) * 64 + c];
            arv[i][e] = attn_r[((size_t)r * 4 + head) * 64 + c];
        }
    float* bufL = (float*)smem + w * 320;               // 64 nodes * 5 floats
    float* bufR = (float*)(smem + 8192) + w * 320;
    #pragma unroll
    for (int j = 0; j < 4; ++j) {
        float s1 = 0.f, s2 = 0.f;
        #pragma unroll
        for (int i = 0; i < 4; ++i)
            #pragma unroll
            for (int e = 0; e < 4; ++e) {
                s1 += acc[i][j][e] * alv[i][e];
                s2 += acc[i][j][e] * arv[i][e];
            }
        int node = j * 16 + l15;                      // 0..63 within wave
        bufL[node * 5 + quad] = s1;
        bufR[node * 5 + quad] = s2;
    }
    float sL = 0.f, sR = 0.f;
    #pragma unroll
    for (int q = 0; q < 4; ++q) {
        sL += bufL[lane * 5 + q];
        sR += bufR[lane * 5 + q];
    }
    int g = mbase + wm * 64 + lane;
    projl[((size_t)r * NPAD + g) * 4 + head] = sL;
    projr[((size_t)r * NPAD + g) * 4 + head] = sR;

    __syncthreads();   // all waves done with loop LDS + proj bufs; bounce may reuse

    // ---- epilogue B: feat bf16 via per-wave LDS bounce + coalesced stores.
    //      Wave sub-tile = 64 rows x 128B. LDS row stride 136B (bank spread).
    unsigned char* bb = smem + w * 8704;
    #pragma unroll
    for (int j = 0; j < 4; ++j) {
        int rr = j * 16 + l15;
        #pragma unroll
        for (int i = 0; i < 4; ++i) {
            ushort2 lo = pk2bf(acc[i][j][0], acc[i][j][1]);
            ushort2 hi = pk2bf(acc[i][j][2], acc[i][j][3]);
            uint2 v;
            v.x = (unsigned)lo.x | ((unsigned)lo.y << 16);
            v.y = (unsigned)hi.x | ((unsigned)hi.y << 16);
            *(uint2*)(bb + rr * 136 + i * 32 + quad * 8) = v;
        }
    }
    asm volatile("s_waitcnt lgkmcnt(0)" ::: "memory");  // cross-lane LDS dep
    #pragma unroll
    for (int q = 0; q < 8; ++q) {
        int rr = q * 8 + (lane >> 3);                 // 8 rows per instruction
        int c  = lane & 7;                            // 8 x 16B = full 128B row
        uint4 v = *(const uint4*)(bb + rr * 136 + c * 16);
        int node = mbase + wm * 64 + rr;
        *(uint4*)(feat + ((size_t)r * NPAD + node) * 256 + nbase + wn * 64 + c * 8) = v;
    }
}

// ---------------------------------------------------------------------------
// K4: fused per-edge logits + CSR scatter with payload (R1-proven form):
//     srcoff[p] = t*NPAD+s  and  exw[p] = float4 of exp(leaky_relu(el+er))
// ---------------------------------------------------------------------------
__global__ void logits_scatter_kernel(
    const int* __restrict__ esrc, const int* __restrict__ edst, const int* __restrict__ etyp,
    const float* __restrict__ projl, const float* __restrict__ projr,
    int* __restrict__ cursor, int* __restrict__ srcoff, float* __restrict__ exw)
{
    int e = blockIdx.x * 256 + threadIdx.x;
    if (e >= N_EDGES) return;
    int s = esrc[e], d = edst[e], t = etyp[e];
    float4 pl = ((const float4*)projl)[(size_t)t * NPAD + s];
    float4 pr = ((const float4*)projr)[(size_t)t * NPAD + d];
    float4 o;
    float v;
    v = pl.x + pr.x; v = v > 0.f ? v : 0.2f * v; o.x = __expf(v);
    v = pl.y + pr.y; v = v > 0.f ? v : 0.2f * v; o.y = __expf(v);
    v = pl.z + pr.z; v = v > 0.f ? v : 0.2f * v; o.z = __expf(v);
    v = pl.w + pr.w; v = v > 0.f ? v : 0.2f * v; o.w = __expf(v);
    int p = atomicAdd(&cursor[d], 1);
    srcoff[p] = t * NPAD + s;
    ((float4*)exw)[p] = o;
}

// ---------------------------------------------------------------------------
// K5: per-node aggregation. NEW this round: FOUR waves per dst node
//     (1 node / 256-thr block, grid 30000), each wave a quarter of the edge
//     range (halves the serial gather chain vs 2-wave R1 form), partials
//     combined through LDS by wave 0. Gather bodies unchanged (proven).
// ---------------------------------------------------------------------------
__global__ __launch_bounds__(256) void aggregate_kernel(
    const int* __restrict__ offsets, const int* __restrict__ srcoff,
    const float* __restrict__ exw, const unsigned short* __restrict__ feat,
    const float* __restrict__ bias, float* __restrict__ out)
{
    __shared__ float sm[3][64][5];
    int wid  = threadIdx.x >> 6;      // 0..3 quarter index
    int v = blockIdx.x;               // grid 30000
    int lane = threadIdx.x & 63;
    int head = lane >> 4;
    int s0 = offsets[v], s1 = offsets[v + 1];
    int len = s1 - s0;
    int lo = s0 + ((len * wid) >> 2);
    int hi = s0 + ((len * (wid + 1)) >> 2);
    float a0 = 0.f, a1 = 0.f, a2 = 0.f, a3 = 0.f, den = 0.f;
    int i = lo;
    for (; i + 8 <= hi; i += 8) {
        int o[8]; float ee[8]; ushort4 ff[8];
        #pragma unroll
        for (int u = 0; u < 8; ++u) { o[u] = srcoff[i + u]; ee[u] = exw[(size_t)(i + u) * 4 + head]; }
        #pragma unroll
        for (int u = 0; u < 8; ++u) ff[u] = *(const ushort4*)(feat + (size_t)o[u] * 256 + lane * 4);
        #pragma unroll
        for (int u = 0; u < 8; ++u) {
            den += ee[u];
            a0 += ee[u] * bf2f(ff[u].x);
            a1 += ee[u] * bf2f(ff[u].y);
            a2 += ee[u] * bf2f(ff[u].z);
            a3 += ee[u] * bf2f(ff[u].w);
        }
    }
    for (; i + 4 <= hi; i += 4) {
        int o[4]; float ee[4]; ushort4 ff[4];
        #pragma unroll
        for (int u = 0; u < 4; ++u) { o[u] = srcoff[i + u]; ee[u] = exw[(size_t)(i + u) * 4 + head]; }
        #pragma unroll
        for (int u = 0; u < 4; ++u) ff[u] = *(const ushort4*)(feat + (size_t)o[u] * 256 + lane * 4);
        #pragma unroll
        for (int u = 0; u < 4; ++u) {
            den += ee[u];
            a0 += ee[u] * bf2f(ff[u].x);
            a1 += ee[u] * bf2f(ff[u].y);
            a2 += ee[u] * bf2f(ff[u].z);
            a3 += ee[u] * bf2f(ff[u].w);
        }
    }
    for (; i + 2 <= hi; i += 2) {
        int o[2]; float ee[2]; ushort4 ff[2];
        #pragma unroll
        for (int u = 0; u < 2; ++u) { o[u] = srcoff[i + u]; ee[u] = exw[(size_t)(i + u) * 4 + head]; }
        #pragma unroll
        for (int u = 0; u < 2; ++u) ff[u] = *(const ushort4*)(feat + (size_t)o[u] * 256 + lane * 4);
        #pragma unroll
        for (int u = 0; u < 2; ++u) {
            den += ee[u];
            a0 += ee[u] * bf2f(ff[u].x);
            a1 += ee[u] * bf2f(ff[u].y);
            a2 += ee[u] * bf2f(ff[u].z);
            a3 += ee[u] * bf2f(ff[u].w);
        }
    }
    if (i < hi) {
        int o0 = srcoff[i];
        float e0 = exw[(size_t)i * 4 + head];
        ushort4 f0 = *(const ushort4*)(feat + (size_t)o0 * 256 + lane * 4);
        den += e0;
        a0 += e0 * bf2f(f0.x);
        a1 += e0 * bf2f(f0.y);
        a2 += e0 * bf2f(f0.z);
        a3 += e0 * bf2f(f0.w);
    }
    if (wid) {
        sm[wid - 1][lane][0] = a0; sm[wid - 1][lane][1] = a1;
        sm[wid - 1][lane][2] = a2; sm[wid - 1][lane][3] = a3;
        sm[wid - 1][lane][4] = den;
    }
    __syncthreads();
    if (wid == 0) {
        #pragma unroll
        for (int q = 0; q < 3; ++q) {
            a0 += sm[q][lane][0]; a1 += sm[q][lane][1];
            a2 += sm[q][lane][2]; a3 += sm[q][lane][3];
            den += sm[q][lane][4];
        }
        float inv = den > 0.f ? 1.f / den : 0.f;
        float4 o;
        o.x = a0 * inv + bias[lane * 4 + 0];
        o.y = a1 * inv + bias[lane * 4 + 1];
        o.z = a2 * inv + bias[lane * 4 + 2];
        o.w = a3 * inv + bias[lane * 4 + 3];
        ((float4*)out)[(size_t)v * 64 + lane] = o;
    }
}

// ---------------------------------------------------------------------------
extern "C" void kernel_launch(void* const* d_in, const int* in_sizes, int n_in,
                              void* d_out, int out_size, void* d_ws, size_t ws_size,
                              hipStream_t stream) {
    const float* x    = (const float*)d_in[0];
    const float* cw   = (const float*)d_in[1];
    const float* al   = (const float*)d_in[2];
    const float* ar   = (const float*)d_in[3];
    const float* bias = (const float*)d_in[4];
    const int* esrc   = (const int*)d_in[5];
    const int* edst   = (const int*)d_in[6];
    const int* etyp   = (const int*)d_in[7];
    float* out        = (float*)d_out;

    char* ws = (char*)d_ws;
    size_t off = 0;
    auto alloc = [&](size_t bytes) { size_t o = off; off += (bytes + 255) & ~(size_t)255; return o; };

    unsigned short* xbf  = (unsigned short*)(ws + alloc((size_t)NPAD * 256 * 2));          // 15.4 MB
    unsigned short* wt   = (unsigned short*)(ws + alloc((size_t)N_RELS * 256 * 256 * 2));  // 1 MB
    unsigned short* feat = (unsigned short*)(ws + alloc((size_t)N_RELS * NPAD * 256 * 2)); // 123.2 MB
    float* projl = (float*)(ws + alloc((size_t)N_RELS * NPAD * 4 * 4));                    // 3.85 MB
    float* projr = (float*)(ws + alloc((size_t)N_RELS * NPAD * 4 * 4));                    // 3.85 MB
    float* exw   = (float*)(ws + alloc((size_t)N_EDGES * 4 * 4));                          // 7.68 MB
    int* srcoff  = (int*)(ws + alloc((size_t)N_EDGES * 4));                                // 1.92 MB
    int* counts  = (int*)(ws + alloc((size_t)N_NODES * 4));
    int* offsets = (int*)(ws + alloc((size_t)(N_NODES + 1) * 4));
    int* cursor  = (int*)(ws + alloc((size_t)N_NODES * 4));
    int* locexcl = (int*)(ws + alloc((size_t)N_NODES * 4));
    int* bsum    = (int*)(ws + alloc((size_t)NB_SCAN * 4));

    hipMemsetAsync(counts, 0, (size_t)N_NODES * 4, stream);

    prep_kernel<<<7683, 256, 0, stream>>>(x, xbf, cw, wt, edst, counts);
    scan1_kernel<<<NB_SCAN, 256, 0, stream>>>(counts, locexcl, bsum);
    scan23_kernel<<<NB_SCAN, 256, 0, stream>>>(locexcl, bsum, offsets, cursor);
    gemm_kernel<<<3760, 256, 0, stream>>>(xbf, wt, al, ar, feat, projl, projr);
    logits_scatter_kernel<<<1875, 256, 0, stream>>>(esrc, edst, etyp, projl, projr,
                                                    cursor, srcoff, exw);
    aggregate_kernel<<<30000, 256, 0, stream>>>(offsets, srcoff, exw, feat, bias, out);
}